// Round 1
// 131.402 us; speedup vs baseline: 1.0225x; 1.0225x over previous
//
#include <hip/hip_runtime.h>
#include <hip/hip_bf16.h>

// Problem constants (fixed by setup_inputs)
#define BATCH 32
#define LSEQ 1025
#define TT 2048
#define NTOK 513      // 1 + (LSEQ-1)/2
#define EMB 384
#define FT 32         // frames per tile
#define NTILE (TT / FT)
// Cutoff: z > 8 contributes < 1.3e-14 (relative < 1e-8 after normalization,
// since every valid frame lies inside a kept token's span -> sum >= ~0.08).
// reach = 8 * sig = 4*d (+eps). Max merged d = 6 -> max reach 24.0001.
// Window: centers in [t0+0.5-24.1, t0+31.5+24.1]; span 79.2; kept-token
// centers are >= 1 frame apart -> <= 81 tokens. WMAX=88 with clamp.
#define WMAX 88
#define INV_SQRT_2PI 0.3989422804014327f

// ---------------------------------------------------------------------------
// prep: merge blank/token pairs, wave-shuffle cumsum + compaction scan
// (fused, 2 barriers), filter tokens (d>=1 && tok!=PAD; d=0 underflows
// exactly since centers are ints and frame midpoints are x.5), ordered
// compaction into 8-byte records {c, (d<<17)|tok*EMB}. Also precomputes the
// per-tile kept-token window [lo, win] (binary search over centers in LDS)
// and the per-batch total duration.
// ---------------------------------------------------------------------------
__global__ __launch_bounds__(256) void prep_kernel(
    const int* __restrict__ text, const int* __restrict__ durs,
    float2* __restrict__ kept, int2* __restrict__ tile_win,
    float* __restrict__ totals) {
  const int b = blockIdx.x;
  const int tid = threadIdx.x;
  const int lane = tid & 63;
  const int wv = tid >> 6;

  __shared__ float s_cc[NTOK];      // compacted centers
  __shared__ float s_wd[4], s_wf[4];

  const int* tb = text + b * LSEQ;
  const int* db = durs + b * LSEQ;

  // 3 contiguous merged elements per thread (171 threads cover 513)
  float d[3], fl[3];
  int tk[3];
  const int nbase = 3 * tid;
#pragma unroll
  for (int j = 0; j < 3; ++j) {
    const int n = nbase + j;
    int dm = 0, t = 0;
    if (n < NTOK) {
      if (n == 0) { dm = db[0]; t = tb[0]; }
      else { dm = db[2 * n - 1] + db[2 * n]; t = tb[2 * n - 1]; }
    }
    d[j] = (float)dm;
    tk[j] = t;
    fl[j] = (dm >= 1 && t != 0) ? 1.0f : 0.0f;
  }
  // local inclusive sums (exact: small ints)
  const float ld1 = d[0] + d[1], ld2 = ld1 + d[2];
  const float lf1 = fl[0] + fl[1], lf2 = lf1 + fl[2];

  // wave inclusive scan of per-thread totals (both scans fused)
  float sd = ld2, sf = lf2;
#pragma unroll
  for (int off = 1; off < 64; off <<= 1) {
    const float od = __shfl_up(sd, off);
    const float of = __shfl_up(sf, off);
    if (lane >= off) { sd += od; sf += of; }
  }
  if (lane == 63) { s_wd[wv] = sd; s_wf[wv] = sf; }
  __syncthreads();

  float wod = 0.f, wof = 0.f;
#pragma unroll
  for (int k = 0; k < 4; ++k) {
    if (k < wv) { wod += s_wd[k]; wof += s_wf[k]; }
  }
  const float exd = wod + sd - ld2;  // exclusive duration prefix
  const float exf = wof + sf - lf2;  // exclusive flag prefix

  const float cum0 = exd + d[0], cum1 = exd + ld1, cum2 = exd + ld2;
  const float fin0 = exf + fl[0], fin1 = exf + lf1, fin2 = exf + lf2;
  const float cums[3] = {cum0, cum1, cum2};
  const float fins[3] = {fin0, fin1, fin2};

#pragma unroll
  for (int j = 0; j < 3; ++j) {
    const int n = nbase + j;
    if (n < NTOK && fl[j] > 0.f) {
      const int pos = (int)fins[j] - 1;
      const float c = cums[j] - 0.5f * d[j];
      const int packed = ((int)d[j] << 17) | (tk[j] * EMB);
      kept[b * NTOK + pos] = make_float2(c, __int_as_float(packed));
      s_cc[pos] = c;
    }
  }
  const float total = s_wd[0] + s_wd[1] + s_wd[2] + s_wd[3];
  const int M = (int)(s_wf[0] + s_wf[1] + s_wf[2] + s_wf[3]);
  if (tid == 0) totals[b] = total;
  __syncthreads();  // s_cc ready

  // per-tile window search (64 tiles, one thread each)
  if (tid < NTILE) {
    const int t0 = tid * FT;
    const float loB = (float)t0 - 23.6f;            // t0+0.5-24.1
    const float hiB = (float)t0 + 55.6f;            // t0+31.5+24.1
    int l = 0, r = M;
    while (l < r) { const int m = (l + r) >> 1; if (s_cc[m] < loB) l = m + 1; else r = m; }
    const int lo = l;
    r = M;
    while (l < r) { const int m = (l + r) >> 1; if (s_cc[m] <= hiB) l = m + 1; else r = m; }
    int wn = l - lo;
    if (wn > WMAX) wn = WMAX;  // unreachable for valid inputs (bound 81)
    tile_win[b * NTILE + tid] = make_int2(lo, wn);
  }
}

__device__ inline void fma4(float4& a, const float w, const float4 v) {
  a.x += w * v.x; a.y += w * v.y; a.z += w * v.z; a.w += w * v.w;
}

// ---------------------------------------------------------------------------
// frames: one block per (batch, 32-frame tile). 256 threads.
// 1) read precomputed token window, stage params to LDS
// 2) dense weight matrix [win][32] into LDS (one mul + exp per pair)
// 3) per-frame sums -> normalization factor (0 beyond total duration)
// 4) mix: thread owns 4 frames x 12 cols; per live token: ONE ds_read_b128
//    of weights + 3 float4 emb loads (L1/L2-resident table) + 48 FMAs
// ---------------------------------------------------------------------------
__global__ __launch_bounds__(256) void frames_kernel(
    const float2* __restrict__ kept, const int2* __restrict__ tile_win,
    const float* __restrict__ totals, const float* __restrict__ emb,
    float* __restrict__ out) {
  const int tile = blockIdx.x;
  const int t0 = tile * FT;
  const int b = blockIdx.y;
  const int tid = threadIdx.x;

  __shared__ float4 s_tk[WMAX];     // {c, inv_sig, coef, off bitcast}
  __shared__ float s_reach[WMAX];   // 4*d (+eps): z<=8 cutoff
  __shared__ float s_w[WMAX * FT];
  __shared__ float s_factor[FT];

  const float total = totals[b];
  const int2 wininfo = tile_win[b * NTILE + tile];
  const int lo = wininfo.x;
  const int win = wininfo.y;
  const float2* kb = kept + b * NTOK;

  // stage token params
  for (int i = tid; i < win; i += 256) {
    const float2 kv = kb[lo + i];
    const int packed = __float_as_int(kv.y);
    const int dI = packed >> 17;
    const float df = (float)dI;
    const float inv_sig = 1.0f / (0.5f * df + 1e-6f);  // matches ref sig
    s_tk[i] = make_float4(kv.x, inv_sig, INV_SQRT_2PI * inv_sig,
                          __int_as_float(packed & 0x1FFFF));
    s_reach[i] = 4.0f * df + 1e-4f;
  }
  __syncthreads();

  // dense weight eval: one mul + one exp per (token, frame)
  const float t0f = (float)t0 + 0.5f;
  const int pairs = win << 5;
  for (int idx = tid; idx < pairs; idx += 256) {
    const int n = idx >> 5, f = idx & (FT - 1);
    const float4 tk = s_tk[n];
    const float z = (t0f + (float)f - tk.x) * tk.y;
    s_w[idx] = tk.z * __expf(-0.5f * z * z);
  }
  __syncthreads();

  // per-frame sums -> factor
  if (tid < FT) {
    float s = 0.f;
    for (int n = 0; n < win; ++n) s += s_w[(n << 5) + tid];
    const float tf = t0f + (float)tid;
    s_factor[tid] = (tf < total) ? 1.0f / (s + 1e-6f) : 0.0f;
  }
  __syncthreads();

  // mix: thread -> 4 frames (group g) x 12 columns
  const int g = tid >> 5;          // 0..7
  const int c = (tid & 31) * 12;   // 32 lanes * 12 = 384 cols
  float4 acc[4][3];
#pragma unroll
  for (int j = 0; j < 4; ++j) {
#pragma unroll
    for (int k = 0; k < 3; ++k) acc[j][k] = make_float4(0.f, 0.f, 0.f, 0.f);
  }

  const float fLo = t0f + (float)(4 * g);
  const float fHi = fLo + 3.0f;
  for (int n = 0; n < win; ++n) {
    const float4 tk = s_tk[n];
    const float rc = s_reach[n];
    if (tk.x + rc < fLo || tk.x - rc > fHi) continue;  // group-uniform skip
    const int off = __float_as_int(tk.w);
    const float4 w4 = *(const float4*)(s_w + (n << 5) + 4 * g);
    const float4 v0 = *(const float4*)(emb + off + c);
    const float4 v1 = *(const float4*)(emb + off + c + 4);
    const float4 v2 = *(const float4*)(emb + off + c + 8);
    const float wv_[4] = {w4.x, w4.y, w4.z, w4.w};
#pragma unroll
    for (int j = 0; j < 4; ++j) {
      const float w = wv_[j];
      fma4(acc[j][0], w, v0);
      fma4(acc[j][1], w, v1);
      fma4(acc[j][2], w, v2);
    }
  }

  // normalize + write (covers every frame incl. invalid -> zeros)
  float* op = out + ((size_t)b * TT + t0 + 4 * g) * EMB + c;
#pragma unroll
  for (int j = 0; j < 4; ++j) {
    const float fac = s_factor[4 * g + j];
    float* row = op + (size_t)j * EMB;
    float4 r0, r1, r2;
    r0.x = acc[j][0].x * fac; r0.y = acc[j][0].y * fac;
    r0.z = acc[j][0].z * fac; r0.w = acc[j][0].w * fac;
    r1.x = acc[j][1].x * fac; r1.y = acc[j][1].y * fac;
    r1.z = acc[j][1].z * fac; r1.w = acc[j][1].w * fac;
    r2.x = acc[j][2].x * fac; r2.y = acc[j][2].y * fac;
    r2.z = acc[j][2].z * fac; r2.w = acc[j][2].w * fac;
    *(float4*)(row) = r0;
    *(float4*)(row + 4) = r1;
    *(float4*)(row + 8) = r2;
  }
}

extern "C" void kernel_launch(void* const* d_in, const int* in_sizes, int n_in,
                              void* d_out, int out_size, void* d_ws,
                              size_t ws_size, hipStream_t stream) {
  const int* text = (const int*)d_in[0];
  const int* durs = (const int*)d_in[1];
  const float* emb = (const float*)d_in[2];
  float* out = (float*)d_out;

  // workspace: kept float2[32*513] (131 KB) | tile_win int2[32*64] (16 KB)
  //            | totals float[32]
  float2* kept = (float2*)d_ws;
  int2* tile_win = (int2*)(kept + BATCH * NTOK);
  float* totals = (float*)(tile_win + BATCH * NTILE);

  prep_kernel<<<BATCH, 256, 0, stream>>>(text, durs, kept, tile_win, totals);
  frames_kernel<<<dim3(NTILE, BATCH), 256, 0, stream>>>(kept, tile_win, totals,
                                                        emb, out);
}

// Round 3
// 125.120 us; speedup vs baseline: 1.0739x; 1.0502x over previous
//
#include <hip/hip_runtime.h>
#include <hip/hip_bf16.h>

// Problem constants (fixed by setup_inputs)
#define BATCH 32
#define LSEQ 1025
#define TT 2048
#define NTOK 513      // 1 + (LSEQ-1)/2
#define EMB 384
#define FT 32         // frames per tile
#define NTILE (TT / FT)
// Cutoff: z > 8 -> w <= exp(-32)*0.8 ~ 1e-14; worst-case normalized
// contribution w/(sum+1e-6) <= 1e-8 even when the true sum ~ 0 (pad runs).
// reach = 8 * sig = 4*d (+eps). Max merged d = 6 -> max reach 24.0001.
// Window: centers in [t0+0.5-24.1, t0+31.5+24.1]; span 79.2; kept-token
// centers are >= 1 frame apart -> <= 81 tokens. WMAX=88 with clamp.
#define WMAX 88
#define INV_SQRT_2PI 0.3989422804014327f

typedef float floatx4 __attribute__((ext_vector_type(4)));  // native vec for nt-store

// ---------------------------------------------------------------------------
// prep: merge blank/token pairs, wave-shuffle cumsum + compaction scan
// (fused, 2 barriers), filter tokens (d>=1 && tok!=PAD; d=0 underflows
// exactly since centers are ints and frame midpoints are x.5), ordered
// compaction into 8-byte records {c, (d<<17)|tok*EMB}. Also precomputes the
// per-tile kept-token window [lo, win] (binary search over centers in LDS)
// and the per-batch total duration.
// ---------------------------------------------------------------------------
__global__ __launch_bounds__(256) void prep_kernel(
    const int* __restrict__ text, const int* __restrict__ durs,
    float2* __restrict__ kept, int2* __restrict__ tile_win,
    float* __restrict__ totals) {
  const int b = blockIdx.x;
  const int tid = threadIdx.x;
  const int lane = tid & 63;
  const int wv = tid >> 6;

  __shared__ float s_cc[NTOK];      // compacted centers
  __shared__ float s_wd[4], s_wf[4];

  const int* tb = text + b * LSEQ;
  const int* db = durs + b * LSEQ;

  // 3 contiguous merged elements per thread (171 threads cover 513)
  float d[3], fl[3];
  int tk[3];
  const int nbase = 3 * tid;
#pragma unroll
  for (int j = 0; j < 3; ++j) {
    const int n = nbase + j;
    int dm = 0, t = 0;
    if (n < NTOK) {
      if (n == 0) { dm = db[0]; t = tb[0]; }
      else { dm = db[2 * n - 1] + db[2 * n]; t = tb[2 * n - 1]; }
    }
    d[j] = (float)dm;
    tk[j] = t;
    fl[j] = (dm >= 1 && t != 0) ? 1.0f : 0.0f;
  }
  // local inclusive sums (exact: small ints)
  const float ld1 = d[0] + d[1], ld2 = ld1 + d[2];
  const float lf1 = fl[0] + fl[1], lf2 = lf1 + fl[2];

  // wave inclusive scan of per-thread totals (both scans fused)
  float sd = ld2, sf = lf2;
#pragma unroll
  for (int off = 1; off < 64; off <<= 1) {
    const float od = __shfl_up(sd, off);
    const float of = __shfl_up(sf, off);
    if (lane >= off) { sd += od; sf += of; }
  }
  if (lane == 63) { s_wd[wv] = sd; s_wf[wv] = sf; }
  __syncthreads();

  float wod = 0.f, wof = 0.f;
#pragma unroll
  for (int k = 0; k < 4; ++k) {
    if (k < wv) { wod += s_wd[k]; wof += s_wf[k]; }
  }
  const float exd = wod + sd - ld2;  // exclusive duration prefix
  const float exf = wof + sf - lf2;  // exclusive flag prefix

  const float cums[3] = {exd + d[0], exd + ld1, exd + ld2};
  const float fins[3] = {exf + fl[0], exf + lf1, exf + lf2};

#pragma unroll
  for (int j = 0; j < 3; ++j) {
    const int n = nbase + j;
    if (n < NTOK && fl[j] > 0.f) {
      const int pos = (int)fins[j] - 1;
      const float c = cums[j] - 0.5f * d[j];
      const int packed = ((int)d[j] << 17) | (tk[j] * EMB);
      kept[b * NTOK + pos] = make_float2(c, __int_as_float(packed));
      s_cc[pos] = c;
    }
  }
  const float total = s_wd[0] + s_wd[1] + s_wd[2] + s_wd[3];
  const int M = (int)(s_wf[0] + s_wf[1] + s_wf[2] + s_wf[3]);
  if (tid == 0) totals[b] = total;
  __syncthreads();  // s_cc ready

  // per-tile window search (64 tiles, one thread each)
  if (tid < NTILE) {
    const int t0 = tid * FT;
    const float loB = (float)t0 - 23.6f;            // t0+0.5-24.1
    const float hiB = (float)t0 + 55.6f;            // t0+31.5+24.1
    int l = 0, r = M;
    while (l < r) { const int m = (l + r) >> 1; if (s_cc[m] < loB) l = m + 1; else r = m; }
    const int lo = l;
    r = M;
    while (l < r) { const int m = (l + r) >> 1; if (s_cc[m] <= hiB) l = m + 1; else r = m; }
    int wn = l - lo;
    if (wn > WMAX) wn = WMAX;  // unreachable for valid inputs (bound 81)
    tile_win[b * NTILE + tid] = make_int2(lo, wn);
  }
}

// ---------------------------------------------------------------------------
// frames: one block per (batch, 32-frame tile). 192 threads.
// 1) read precomputed token window, stage params to LDS
// 2) dense weight matrix [win][32] into LDS (one mul + exp per pair)
// 3) per-frame sums -> normalization factor (0 beyond total duration)
// 4) mix: thread owns 16 frames (half-tile fh) x 4 CONTIGUOUS cols:
//    emb loads and output stores are full-width coalesced (lanes 16B apart);
//    weight reads are same-address LDS broadcasts (free). Per live token:
//    1 coalesced float4 emb load + 4 broadcast b128 weight reads + 64 FMA.
// ---------------------------------------------------------------------------
__global__ __launch_bounds__(192) void frames_kernel(
    const float2* __restrict__ kept, const int2* __restrict__ tile_win,
    const float* __restrict__ totals, const float* __restrict__ emb,
    float* __restrict__ out) {
  const int tile = blockIdx.x;
  const int t0 = tile * FT;
  const int b = blockIdx.y;
  const int tid = threadIdx.x;

  __shared__ float4 s_tk[WMAX];     // {c, inv_sig, coef, off bitcast}
  __shared__ float s_reach[WMAX];   // 4*d (+eps): z<=8 cutoff
  __shared__ float s_w[WMAX * FT];
  __shared__ float s_factor[FT];

  const float total = totals[b];
  const int2 wininfo = tile_win[b * NTILE + tile];
  const int lo = wininfo.x;
  const int win = wininfo.y;
  const float2* kb = kept + b * NTOK;

  // stage token params
  for (int i = tid; i < win; i += 192) {
    const float2 kv = kb[lo + i];
    const int packed = __float_as_int(kv.y);
    const int dI = packed >> 17;
    const float df = (float)dI;
    const float inv_sig = 1.0f / (0.5f * df + 1e-6f);  // matches ref sig
    s_tk[i] = make_float4(kv.x, inv_sig, INV_SQRT_2PI * inv_sig,
                          __int_as_float(packed & 0x1FFFF));
    s_reach[i] = 4.0f * df + 1e-4f;
  }
  __syncthreads();

  // dense weight eval: one mul + one exp per (token, frame)
  const float t0f = (float)t0 + 0.5f;
  const int pairs = win << 5;
  for (int idx = tid; idx < pairs; idx += 192) {
    const int n = idx >> 5, f = idx & (FT - 1);
    const float4 tk = s_tk[n];
    const float z = (t0f + (float)f - tk.x) * tk.y;
    s_w[idx] = tk.z * __expf(-0.5f * z * z);
  }
  __syncthreads();

  // per-frame sums -> factor (stride-1 across lanes: conflict-free)
  if (tid < FT) {
    float s = 0.f;
    for (int n = 0; n < win; ++n) s += s_w[(n << 5) + tid];
    const float tf = t0f + (float)tid;
    s_factor[tid] = (tf < total) ? 1.0f / (s + 1e-6f) : 0.0f;
  }
  __syncthreads();

  // mix: thread -> half-tile fh (16 frames) x 4 contiguous columns
  const int fh = tid / 96;
  const int cg = (tid % 96) * 4;
  const int fbase = fh * 16;
  float4 acc[16];
#pragma unroll
  for (int k = 0; k < 16; ++k) acc[k] = make_float4(0.f, 0.f, 0.f, 0.f);

  const float fLo = t0f + (float)fbase;
  const float fHi = fLo + 15.0f;
  for (int n = 0; n < win; ++n) {
    const float4 tk = s_tk[n];
    const float rc = s_reach[n];
    if (tk.x + rc < fLo || tk.x - rc > fHi) continue;  // uniform skip
    const int off = __float_as_int(tk.w);
    const float4 v = *(const float4*)(emb + off + cg);     // coalesced
    const float4* wp = (const float4*)(s_w + (n << 5) + fbase);  // broadcast
#pragma unroll
    for (int q = 0; q < 4; ++q) {
      const float4 w4 = wp[q];
      float4& a0 = acc[4 * q + 0];
      a0.x += w4.x * v.x; a0.y += w4.x * v.y; a0.z += w4.x * v.z; a0.w += w4.x * v.w;
      float4& a1 = acc[4 * q + 1];
      a1.x += w4.y * v.x; a1.y += w4.y * v.y; a1.z += w4.y * v.z; a1.w += w4.y * v.w;
      float4& a2 = acc[4 * q + 2];
      a2.x += w4.z * v.x; a2.y += w4.z * v.y; a2.z += w4.z * v.z; a2.w += w4.z * v.w;
      float4& a3 = acc[4 * q + 3];
      a3.x += w4.w * v.x; a3.y += w4.w * v.y; a3.z += w4.w * v.z; a3.w += w4.w * v.w;
    }
  }

  // normalize + nontemporal coalesced write (covers invalid frames -> zeros)
  const size_t obase = ((size_t)b * TT + t0 + fbase) * EMB + cg;
#pragma unroll
  for (int k = 0; k < 16; ++k) {
    const float fac = s_factor[fbase + k];
    floatx4 r;
    r.x = acc[k].x * fac; r.y = acc[k].y * fac;
    r.z = acc[k].z * fac; r.w = acc[k].w * fac;
    __builtin_nontemporal_store(r, (floatx4*)(out + obase + (size_t)k * EMB));
  }
}

extern "C" void kernel_launch(void* const* d_in, const int* in_sizes, int n_in,
                              void* d_out, int out_size, void* d_ws,
                              size_t ws_size, hipStream_t stream) {
  const int* text = (const int*)d_in[0];
  const int* durs = (const int*)d_in[1];
  const float* emb = (const float*)d_in[2];
  float* out = (float*)d_out;

  // workspace: kept float2[32*513] (131 KB) | tile_win int2[32*64] (16 KB)
  //            | totals float[32]
  float2* kept = (float2*)d_ws;
  int2* tile_win = (int2*)(kept + BATCH * NTOK);
  float* totals = (float*)(tile_win + BATCH * NTILE);

  prep_kernel<<<BATCH, 256, 0, stream>>>(text, durs, kept, tile_win, totals);
  frames_kernel<<<dim3(NTILE, BATCH), 192, 0, stream>>>(kept, tile_win, totals,
                                                        emb, out);
}